// Round 3
// 200.110 us; speedup vs baseline: 1.0306x; 1.0306x over previous
//
#include <hip/hip_runtime.h>

// ---------------------------------------------------------------------------
// Fused attention: x@Wqkv^T -> RoPE -> masked softmax attention -> @Wproj^T+b
// B=2, N=2048, C=1024, H=16, D=64.  All MFMA compute in bf16, fp32 accum.
//
// LESSON (R5): do NOT fuse RoPE-scatter into the GEMM epilogue with scalar
// 2B global stores — partial-sector writes caused ~16x HBM write
// amplification and a 6x kernel regression.  Dense u16x8 stores only.
//
// R6: flash_attn was VALU-issue bound (VALUBusy 49%, MfmaUtil 21%).  Changes:
//   a) SCL folded into Q at rope_scatter; masking moved out of the softmax:
//      V rows of masked keys zeroed at scatter, denominator l computed as
//      P @ mask_vec (bf16 0/1 B-fragment) instead of P @ ones.  The inner
//      softmax is now a bare exp2(s) — no fmaf, no fbias loads.
//   b) tile body reordered: all QK^T MFMAs -> softmax(keys 0..31) ->
//      PV(ks=0) -> softmax(keys 32..63) -> PV(ks=1), so softmax VALU
//      overlaps PV MFMA latency.
//   c) s_setprio(1) around MFMA clusters (T5).
// (R7/R8 = R6 resubmitted verbatim: both benches failed on
//  GPUAcquisitionTimeout — the experiment has not run yet.)
// ---------------------------------------------------------------------------

typedef __attribute__((ext_vector_type(8))) short          s16x8;
typedef __attribute__((ext_vector_type(8))) unsigned short u16x8;
typedef __attribute__((ext_vector_type(4))) unsigned short u16x4;
typedef __attribute__((ext_vector_type(4))) float          f32x4;

#define MFMA_BF16(a, b, c) __builtin_amdgcn_mfma_f32_16x16x32_bf16((a), (b), (c), 0, 0, 0)

// async global->LDS, 16B per lane (dest = wave-uniform base + lane*16)
#define GLD_TO_LDS(gp, lp) __builtin_amdgcn_global_load_lds(                  \
    (const __attribute__((address_space(1))) void*)(gp),                      \
    (__attribute__((address_space(3))) void*)(lp), 16, 0, 0)

__device__ __forceinline__ unsigned short f2bf(float f) {
    union { float f; unsigned int u; } v; v.f = f;
    unsigned int u = v.u;
    unsigned int r = u + 0x7FFFu + ((u >> 16) & 1u);   // round-to-nearest-even
    return (unsigned short)(r >> 16);
}
__device__ __forceinline__ float bf2f(unsigned short h) {
    union { unsigned int u; float f; } v; v.u = ((unsigned int)h) << 16;
    return v.f;
}

// ---------------------------------------------------------------------------
// prep: fp32->bf16 converts for x, w_qkv, w_proj + mask -> bf16 0/1 vector.
// Block ranges are exact multiples of 256 threads:
// [0,4096) x, [4096,7168) w_qkv, [7168,8192) w_proj, [8192,8208) mask.
// ---------------------------------------------------------------------------
__global__ __launch_bounds__(256) void prep(const float* __restrict__ x,
                                            const float* __restrict__ wqkv,
                                            const float* __restrict__ wproj,
                                            const int* __restrict__ m,
                                            unsigned short* __restrict__ xb,
                                            unsigned short* __restrict__ wqkvb,
                                            unsigned short* __restrict__ wprojb,
                                            unsigned short* __restrict__ mb) {
    int blk = blockIdx.x, tid = threadIdx.x;
    if (blk < 8192) {
        const float* src; unsigned short* dst; int i;
        if (blk < 4096)      { src = x;     dst = xb;     i = blk * 256 + tid; }
        else if (blk < 7168) { src = wqkv;  dst = wqkvb;  i = (blk - 4096) * 256 + tid; }
        else                 { src = wproj; dst = wprojb; i = (blk - 7168) * 256 + tid; }
        f32x4 v = ((const f32x4*)src)[i];
        u16x4 o;
        o[0] = f2bf(v[0]); o[1] = f2bf(v[1]); o[2] = f2bf(v[2]); o[3] = f2bf(v[3]);
        ((u16x4*)dst)[i] = o;
    } else {
        int i = (blk - 8192) * 256 + tid;
        mb[i] = (m[i] == 0) ? (unsigned short)0 : (unsigned short)0x3F80;  // bf16 1.0
    }
}

// ---------------------------------------------------------------------------
// bf16 GEMM, C[M,N] = A[M,K] * B[N,K]^T, bf16 out.  128x128 tile, BK=64,
// 256 threads = 4 waves in 2x2, each wave 64x64 via 4x4 frags of 16x16x32.
// Staging via global_load_lds(16B) with XOR seg-swizzle (seg ^= row&7).
// ---------------------------------------------------------------------------
__global__ __launch_bounds__(256) void gemm_bt(const unsigned short* __restrict__ A,
                                               const unsigned short* __restrict__ B,
                                               unsigned short* __restrict__ C,
                                               int M, int N, int K) {
    __shared__ unsigned short Al[128][64];
    __shared__ unsigned short Bl[128][64];
    const int tid  = threadIdx.x;
    const int lane = tid & 63;
    const int qd   = lane >> 4;     // quad 0..3
    const int cc   = lane & 15;
    const int wave = tid >> 6;
    const int wr   = wave >> 1, wc = wave & 1;
    const int m0   = blockIdx.y * 128, n0 = blockIdx.x * 128;
    unsigned short* Alf = &Al[0][0];
    unsigned short* Blf = &Bl[0][0];

    f32x4 acc[4][4];
#pragma unroll
    for (int i = 0; i < 4; i++)
#pragma unroll
        for (int j = 0; j < 4; j++) acc[i][j] = (f32x4){0.f, 0.f, 0.f, 0.f};

    for (int k0 = 0; k0 < K; k0 += 64) {
#pragma unroll
        for (int t = 0; t < 4; t++) {
            int idx = t * 256 + tid;                 // 0..1023
            int row = idx >> 3, sg = (idx & 7) ^ (row & 7);
            GLD_TO_LDS(A + (size_t)(m0 + row) * K + k0 + sg * 8, Alf + idx * 8);
            GLD_TO_LDS(B + (size_t)(n0 + row) * K + k0 + sg * 8, Blf + idx * 8);
        }
        __syncthreads();
#pragma unroll
        for (int ks = 0; ks < 64; ks += 32) {
            const int s4 = ks >> 3;                  // 0 or 4
            s16x8 af[4], bf[4];
#pragma unroll
            for (int i = 0; i < 4; i++) {
                int r = wr * 64 + i * 16 + cc;
                af[i] = *(const s16x8*)&Al[r][((s4 + qd) ^ (r & 7)) * 8];
            }
#pragma unroll
            for (int j = 0; j < 4; j++) {
                int r = wc * 64 + j * 16 + cc;
                bf[j] = *(const s16x8*)&Bl[r][((s4 + qd) ^ (r & 7)) * 8];
            }
#pragma unroll
            for (int i = 0; i < 4; i++)
#pragma unroll
                for (int j = 0; j < 4; j++)
                    acc[i][j] = MFMA_BF16(af[i], bf[j], acc[i][j]);
        }
        __syncthreads();
    }
    // epilogue: C/D layout col=lane&15, row=quad*4+reg
#pragma unroll
    for (int i = 0; i < 4; i++)
#pragma unroll
        for (int j = 0; j < 4; j++)
#pragma unroll
            for (int r = 0; r < 4; r++) {
                int row = m0 + wr * 64 + i * 16 + qd * 4 + r;
                int col = n0 + wc * 64 + j * 16 + cc;
                C[(size_t)row * N + col] = f2bf(acc[i][j][r]);
            }
}

// ---------------------------------------------------------------------------
// RoPE + scatter: qkv[4096,3072] bf16 -> Q[B,H,N,D] (scaled by SCL), K (RoPE'd),
// V transposed -> Vt[B,H,D,N] with masked-key rows zeroed.
// One block per (b,h,64-row tile).  All global stores dense u16x8.
// ---------------------------------------------------------------------------
__global__ __launch_bounds__(256) void rope_scatter(const unsigned short* __restrict__ qkv,
                                                    const int* __restrict__ msk,
                                                    unsigned short* __restrict__ Q,
                                                    unsigned short* __restrict__ Kg,
                                                    unsigned short* __restrict__ Vt) {
    const int N = 2048, H = 16, D = 64, C3 = 3072;
    const float SCL = 0.18033688f;              // 0.125 * log2(e), folded into Q
    __shared__ unsigned short vl[64][65];       // +1 pad for transpose reads
    const int nt = blockIdx.x, h = blockIdx.y, b = blockIdx.z;
    const int n0 = nt * 64;
    const int tid = threadIdx.x;
    const size_t bh = (size_t)b * H + h;
#pragma unroll
    for (int it = 0; it < 2; it++) {
        int idx = tid + it * 256;           // 0..511
        int row = idx >> 3, seg = idx & 7;
        int d0 = seg * 8;
        int n = n0 + row;
        size_t rb = ((size_t)b * N + n) * C3;
        int keep = msk[(size_t)b * N + n];
        u16x8 qv = *(const u16x8*)&qkv[rb + h * 64 + d0];
        u16x8 qp = *(const u16x8*)&qkv[rb + h * 64 + (d0 ^ 32)];
        u16x8 kv = *(const u16x8*)&qkv[rb + 1024 + h * 64 + d0];
        u16x8 kp = *(const u16x8*)&qkv[rb + 1024 + h * 64 + (d0 ^ 32)];
        u16x8 vv = *(const u16x8*)&qkv[rb + 2048 + h * 64 + d0];
        u16x8 qo, ko;
        float sgn = (d0 < 32) ? -1.0f : 1.0f;   // rotate_half sign
#pragma unroll
        for (int j = 0; j < 8; j++) {
            int jj = (d0 & 31) + j;                              // freq index
            float th = (float)n * exp2f(-0.34375f * (float)jj);  // 2048^(-jj/32)
            float cth = cosf(th), sth = sinf(th);
            qo[j] = f2bf((bf2f(qv[j]) * cth + sgn * bf2f(qp[j]) * sth) * SCL);
            ko[j] = f2bf(bf2f(kv[j]) * cth + sgn * bf2f(kp[j]) * sth);
            vl[row][d0 + j] = keep ? vv[j] : (unsigned short)0;
        }
        *(u16x8*)&Q[(bh * N + n) * D + d0]  = qo;
        *(u16x8*)&Kg[(bh * N + n) * D + d0] = ko;
    }
    __syncthreads();
    // transposed V write: Vt[b,h,d,n]
#pragma unroll
    for (int it = 0; it < 2; it++) {
        int idx = tid + it * 256;
        int drow = idx >> 3, nseg = idx & 7;
        u16x8 ov;
#pragma unroll
        for (int j = 0; j < 8; j++) ov[j] = vl[nseg * 8 + j][drow];
        *(u16x8*)&Vt[(bh * D + drow) * N + n0 + nseg * 8] = ov;
    }
}

// ---------------------------------------------------------------------------
// Flash attention: double-buffered DMA staging of K AND V, S^T orientation,
// softmax-lite (no running max), l via MFMA-with-mask (handles key padding),
// pure exp2 inner loop (SCL pre-folded into Q, masked V rows pre-zeroed).
// Block = (128-q-tile, h, b); 4 waves x 32 q-rows; K-tiles of 64.
// Tile body pipelined: QK^T(all) -> sm(0,1) -> PV(ks0) -> sm(2,3) -> PV(ks1).
// ---------------------------------------------------------------------------
__global__ __launch_bounds__(256, 2) void flash_attn(const unsigned short* __restrict__ Q,
                                                     const unsigned short* __restrict__ Kg,
                                                     const unsigned short* __restrict__ Vt,
                                                     const unsigned short* __restrict__ mb,
                                                     unsigned short* __restrict__ Og) {
    const int N = 2048, H = 16, D = 64;
    __shared__ unsigned short Kl0[64][64], Kl1[64][64];   // [key][d] swizzled
    __shared__ unsigned short Vl0[64][64], Vl1[64][64];   // [d][key] swizzled
    __shared__ unsigned short Pl[4][32][76];   // [wave][query][key], stride 76
    const int tid  = threadIdx.x;
    const int lane = tid & 63;
    const int wave = tid >> 6;
    const int qd   = lane >> 4;
    const int cc   = lane & 15;
    const int qt = blockIdx.x, h = blockIdx.y, b = blockIdx.z;
    const int q0 = qt * 128;
    const size_t bh = (size_t)b * H + h;

    // Q B-frags: B[n=q=lane&15][k=d=quad*8+j]  (Q already scaled by SCL)
    s16x8 qf[2][2];
#pragma unroll
    for (int fr = 0; fr < 2; fr++) {
        const unsigned short* Qb = Q + (bh * N + q0 + wave * 32 + fr * 16 + cc) * D;
        qf[fr][0] = *(const s16x8*)(Qb + qd * 8);
        qf[fr][1] = *(const s16x8*)(Qb + 32 + qd * 8);
    }

    f32x4 o[2][4], lacc[2];
#pragma unroll
    for (int fr = 0; fr < 2; fr++) {
        lacc[fr] = (f32x4){0.f, 0.f, 0.f, 0.f};
#pragma unroll
        for (int db = 0; db < 4; db++) o[fr][db] = (f32x4){0.f, 0.f, 0.f, 0.f};
    }

    const unsigned short* Kbase = Kg + bh * N * D;
    const unsigned short* Vbase = Vt + bh * D * N;
    const unsigned short* mbase = mb + (size_t)b * N;   // bf16 0/1 mask vector
    const int row_s = tid >> 3, sg_s = (tid & 7) ^ ((tid >> 3) & 7);
    const int row_s2 = (tid + 256) >> 3, sg_s2 = (tid & 7) ^ (((tid + 256) >> 3) & 7);

    auto issue = [&](int k0, unsigned short* Kb, unsigned short* Vb) {
        GLD_TO_LDS(Kbase + (size_t)(k0 + row_s) * D + sg_s * 8,  Kb + tid * 8);
        GLD_TO_LDS(Vbase + (size_t)row_s * N + k0 + sg_s * 8,    Vb + tid * 8);
        GLD_TO_LDS(Kbase + (size_t)(k0 + row_s2) * D + sg_s2 * 8, Kb + (tid + 256) * 8);
        GLD_TO_LDS(Vbase + (size_t)row_s2 * N + k0 + sg_s2 * 8,   Vb + (tid + 256) * 8);
    };

    auto compute = [&](int k0, const unsigned short (*Kb)[64], const unsigned short (*Vb)[64]) {
        // ---- QK^T: all 4 key-subtiles into registers --------------------
        f32x4 sst[4][2];
        __builtin_amdgcn_s_setprio(1);
#pragma unroll
        for (int sub = 0; sub < 4; sub++) {
            int kr = sub * 16 + cc;
            s16x8 kf0 = *(const s16x8*)&Kb[kr][((0 + qd) ^ (kr & 7)) * 8];
            s16x8 kf1 = *(const s16x8*)&Kb[kr][((4 + qd) ^ (kr & 7)) * 8];
#pragma unroll
            for (int fr = 0; fr < 2; fr++) {
                f32x4 s = (f32x4){0.f, 0.f, 0.f, 0.f};
                s = MFMA_BF16(kf0, qf[fr][0], s);
                sst[sub][fr] = MFMA_BF16(kf1, qf[fr][1], s);
            }
        }
        __builtin_amdgcn_s_setprio(0);

        // ---- softmax-lite for one 16-key subtile: p = exp2(s), pack -> Pl
        auto sm = [&](int sub) {
#pragma unroll
            for (int fr = 0; fr < 2; fr++) {
                f32x4 s = sst[sub][fr];
                float p0 = exp2f(s[0]);
                float p1 = exp2f(s[1]);
                float p2 = exp2f(s[2]);
                float p3 = exp2f(s[3]);
                unsigned int w0 = __builtin_amdgcn_perm(
                    __builtin_bit_cast(unsigned int, p1),
                    __builtin_bit_cast(unsigned int, p0), 0x07060302u);
                unsigned int w1 = __builtin_amdgcn_perm(
                    __builtin_bit_cast(unsigned int, p3),
                    __builtin_bit_cast(unsigned int, p2), 0x07060302u);
                unsigned long long w = ((unsigned long long)w1 << 32) | w0;
                *(unsigned long long*)&Pl[wave][fr * 16 + cc][sub * 16 + qd * 4] = w;
            }
        };

        // ---- O += P V ; l += P @ mask, for one 32-key half --------------
        auto pv = [&](int ks) {
            s16x8 mf = *(const s16x8*)&mbase[k0 + ks * 32 + qd * 8];
            s16x8 vfl[4];
#pragma unroll
            for (int db = 0; db < 4; db++) {
                int vr = db * 16 + cc;
                vfl[db] = *(const s16x8*)&Vb[vr][((ks * 4 + qd) ^ (vr & 7)) * 8];
            }
            __builtin_amdgcn_s_setprio(1);
#pragma unroll
            for (int fr = 0; fr < 2; fr++) {
                s16x8 pf = *(const s16x8*)&Pl[wave][fr * 16 + cc][ks * 32 + qd * 8];
                lacc[fr] = MFMA_BF16(pf, mf, lacc[fr]);
#pragma unroll
                for (int db = 0; db < 4; db++)
                    o[fr][db] = MFMA_BF16(pf, vfl[db], o[fr][db]);
            }
            __builtin_amdgcn_s_setprio(0);
        };

        sm(0); sm(1);     // keys 0..31 ready (overlaps S-MFMA latency of subs 2,3)
        pv(0);            // PV on keys 0..31
        sm(2); sm(3);     // keys 32..63 exp/pack overlap PV(ks=0) MFMA latency
        pv(1);            // PV on keys 32..63
    };

    issue(0, &Kl0[0][0], &Vl0[0][0]);
    __syncthreads();
    for (int it = 0; it < 32; it += 2) {
        int k0 = it * 64;
        if (it + 1 < 32) issue(k0 + 64, &Kl1[0][0], &Vl1[0][0]);
        compute(k0, Kl0, Vl0);
        __syncthreads();
        if (it + 2 < 32) issue(k0 + 128, &Kl0[0][0], &Vl0[0][0]);
        compute(k0 + 64, Kl1, Vl1);
        __syncthreads();
    }

    // epilogue: lacc rows == o rows (query = fr*16 + qd*4 + r)
#pragma unroll
    for (int fr = 0; fr < 2; fr++) {
        float linv[4];
#pragma unroll
        for (int r = 0; r < 4; r++) linv[r] = 1.0f / lacc[fr][r];
#pragma unroll
        for (int db = 0; db < 4; db++)
#pragma unroll
            for (int r = 0; r < 4; r++) {
                int n = q0 + wave * 32 + fr * 16 + qd * 4 + r;
                Og[((size_t)b * N + n) * 1024 + h * 64 + db * 16 + cc] =
                    f2bf(o[fr][db][r] * linv[r]);
            }
    }
}

// ---------------------------------------------------------------------------
// Projection GEMM: out[4096,1024] = attno[4096,1024] @ w_proj^T + bias, fp32.
// 128x64 tile -> 512 blocks = 2 blocks/CU.
// ---------------------------------------------------------------------------
__global__ __launch_bounds__(256) void gemm_proj(const unsigned short* __restrict__ A,
                                                 const unsigned short* __restrict__ B,
                                                 float* __restrict__ C,
                                                 const float* __restrict__ bias) {
    const int NN = 1024, K = 1024;
    __shared__ unsigned short Al[128][64];
    __shared__ unsigned short Bl[64][64];
    const int tid  = threadIdx.x;
    const int lane = tid & 63;
    const int qd   = lane >> 4;
    const int cc   = lane & 15;
    const int wave = tid >> 6;
    const int wr   = wave >> 1, wc = wave & 1;
    const int m0   = blockIdx.y * 128, n0 = blockIdx.x * 64;
    unsigned short* Alf = &Al[0][0];
    unsigned short* Blf = &Bl[0][0];

    f32x4 acc[4][2];
#pragma unroll
    for (int i = 0; i < 4; i++)
#pragma unroll
        for (int j = 0; j < 2; j++) acc[i][j] = (f32x4){0.f, 0.f, 0.f, 0.f};

    for (int k0 = 0; k0 < K; k0 += 64) {
#pragma unroll
        for (int t = 0; t < 4; t++) {
            int idx = t * 256 + tid;
            int row = idx >> 3, sg = (idx & 7) ^ (row & 7);
            GLD_TO_LDS(A + (size_t)(m0 + row) * K + k0 + sg * 8, Alf + idx * 8);
        }
#pragma unroll
        for (int t = 0; t < 2; t++) {
            int idx = t * 256 + tid;
            int row = idx >> 3, sg = (idx & 7) ^ (row & 7);
            GLD_TO_LDS(B + (size_t)(n0 + row) * K + k0 + sg * 8, Blf + idx * 8);
        }
        __syncthreads();
#pragma unroll
        for (int ks = 0; ks < 64; ks += 32) {
            const int s4 = ks >> 3;
            s16x8 af[4], bf[2];
#pragma unroll
            for (int i = 0; i < 4; i++) {
                int r = wr * 64 + i * 16 + cc;
                af[i] = *(const s16x8*)&Al[r][((s4 + qd) ^ (r & 7)) * 8];
            }
#pragma unroll
            for (int j = 0; j < 2; j++) {
                int r = wc * 32 + j * 16 + cc;
                bf[j] = *(const s16x8*)&Bl[r][((s4 + qd) ^ (r & 7)) * 8];
            }
#pragma unroll
            for (int i = 0; i < 4; i++)
#pragma unroll
                for (int j = 0; j < 2; j++)
                    acc[i][j] = MFMA_BF16(af[i], bf[j], acc[i][j]);
        }
        __syncthreads();
    }
#pragma unroll
    for (int i = 0; i < 4; i++)
#pragma unroll
        for (int j = 0; j < 2; j++)
#pragma unroll
            for (int r = 0; r < 4; r++) {
                int row = m0 + wr * 64 + i * 16 + qd * 4 + r;
                int col = n0 + wc * 32 + j * 16 + cc;
                C[(size_t)row * NN + col] = acc[i][j][r] + bias[col];
            }
}

// ---------------------------------------------------------------------------
extern "C" void kernel_launch(void* const* d_in, const int* in_sizes, int n_in,
                              void* d_out, int out_size, void* d_ws, size_t ws_size,
                              hipStream_t stream) {
    const float* x      = (const float*)d_in[0];
    const float* w_qkv  = (const float*)d_in[1];
    const float* w_proj = (const float*)d_in[2];
    const float* b_proj = (const float*)d_in[3];
    const int*   mask   = (const int*)d_in[4];
    float* out = (float*)d_out;

    // workspace layout (bf16 elements), ~72 MB
    unsigned short* ws     = (unsigned short*)d_ws;
    unsigned short* xb     = ws;                                  // 4096*1024
    unsigned short* wqkvb  = xb     + (size_t)4096 * 1024;        // 3072*1024
    unsigned short* wprojb = wqkvb  + (size_t)3072 * 1024;        // 1024*1024
    unsigned short* qkv    = wprojb + (size_t)1024 * 1024;        // 4096*3072
    unsigned short* Qm     = qkv    + (size_t)4096 * 3072;        // 32*2048*64
    unsigned short* Km     = Qm     + (size_t)32 * 2048 * 64;
    unsigned short* Vtm    = Km     + (size_t)32 * 2048 * 64;
    unsigned short* attno  = Vtm    + (size_t)32 * 2048 * 64;     // 4096*1024
    unsigned short* maskbf = attno  + (size_t)4096 * 1024;        // 2*2048 bf16

    // converts + bf16 mask vector, one launch
    prep<<<8208, 256, 0, stream>>>(x, w_qkv, w_proj, mask, xb, wqkvb, wprojb, maskbf);
    // qkv = x @ w_qkv^T   [4096, 3072]
    gemm_bt<<<dim3(24, 32), 256, 0, stream>>>(xb, wqkvb, qkv, 4096, 3072, 1024);
    // RoPE + scatter to Q (SCL-scaled) / K [B,H,N,D] and Vt [B,H,D,N] (masked rows zeroed)
    rope_scatter<<<dim3(32, 16, 2), 256, 0, stream>>>(qkv, mask, Qm, Km, Vtm);
    // attention: 128-row Q tiles, double-buffered staging
    flash_attn<<<dim3(16, 16, 2), 256, 0, stream>>>(Qm, Km, Vtm, maskbf, attno);
    // out = attn_out @ w_proj^T + b_proj
    gemm_proj<<<dim3(16, 32), 256, 0, stream>>>(attno, wprojb, out, b_proj);
}

// Round 4
// 199.407 us; speedup vs baseline: 1.0343x; 1.0035x over previous
//
#include <hip/hip_runtime.h>

// ---------------------------------------------------------------------------
// Fused attention: x@Wqkv^T -> RoPE -> masked softmax attention -> @Wproj^T+b
// B=2, N=2048, C=1024, H=16, D=64.  All MFMA compute in bf16, fp32 accum.
//
// LESSON (R5): do NOT fuse RoPE-scatter into the GEMM epilogue with scalar
// 2B global stores — partial-sector writes caused ~16x HBM write
// amplification and a 6x kernel regression.  Dense u16x8 stores only.
//
// R6 (measured): mask/SCL folded out of inner softmax + sm/pv interleave +
// setprio: flash_attn 71.6 -> 64.2 us.  VALUBusy stayed ~49% -> the limit is
// VALU/MFMA overlap with only 2 waves/SIMD (Occupancy 17%).
//
// R9 (this round): flash_attn re-partitioned 4 waves x 32 q-rows ->
// 8 waves x 16 q-rows (512 threads), same q-tile(128)/LDS/grid.  16 waves/CU
// = 4/SIMD so VALU of one wave overlaps MFMA of another.  Mask fragments
// hoisted above QK^T MFMAs.
// ---------------------------------------------------------------------------

typedef __attribute__((ext_vector_type(8))) short          s16x8;
typedef __attribute__((ext_vector_type(8))) unsigned short u16x8;
typedef __attribute__((ext_vector_type(4))) unsigned short u16x4;
typedef __attribute__((ext_vector_type(4))) float          f32x4;

#define MFMA_BF16(a, b, c) __builtin_amdgcn_mfma_f32_16x16x32_bf16((a), (b), (c), 0, 0, 0)

// async global->LDS, 16B per lane (dest = wave-uniform base + lane*16)
#define GLD_TO_LDS(gp, lp) __builtin_amdgcn_global_load_lds(                  \
    (const __attribute__((address_space(1))) void*)(gp),                      \
    (__attribute__((address_space(3))) void*)(lp), 16, 0, 0)

__device__ __forceinline__ unsigned short f2bf(float f) {
    union { float f; unsigned int u; } v; v.f = f;
    unsigned int u = v.u;
    unsigned int r = u + 0x7FFFu + ((u >> 16) & 1u);   // round-to-nearest-even
    return (unsigned short)(r >> 16);
}
__device__ __forceinline__ float bf2f(unsigned short h) {
    union { unsigned int u; float f; } v; v.u = ((unsigned int)h) << 16;
    return v.f;
}

// ---------------------------------------------------------------------------
// prep: fp32->bf16 converts for x, w_qkv, w_proj + mask -> bf16 0/1 vector.
// Block ranges are exact multiples of 256 threads:
// [0,4096) x, [4096,7168) w_qkv, [7168,8192) w_proj, [8192,8208) mask.
// ---------------------------------------------------------------------------
__global__ __launch_bounds__(256) void prep(const float* __restrict__ x,
                                            const float* __restrict__ wqkv,
                                            const float* __restrict__ wproj,
                                            const int* __restrict__ m,
                                            unsigned short* __restrict__ xb,
                                            unsigned short* __restrict__ wqkvb,
                                            unsigned short* __restrict__ wprojb,
                                            unsigned short* __restrict__ mb) {
    int blk = blockIdx.x, tid = threadIdx.x;
    if (blk < 8192) {
        const float* src; unsigned short* dst; int i;
        if (blk < 4096)      { src = x;     dst = xb;     i = blk * 256 + tid; }
        else if (blk < 7168) { src = wqkv;  dst = wqkvb;  i = (blk - 4096) * 256 + tid; }
        else                 { src = wproj; dst = wprojb; i = (blk - 7168) * 256 + tid; }
        f32x4 v = ((const f32x4*)src)[i];
        u16x4 o;
        o[0] = f2bf(v[0]); o[1] = f2bf(v[1]); o[2] = f2bf(v[2]); o[3] = f2bf(v[3]);
        ((u16x4*)dst)[i] = o;
    } else {
        int i = (blk - 8192) * 256 + tid;
        mb[i] = (m[i] == 0) ? (unsigned short)0 : (unsigned short)0x3F80;  // bf16 1.0
    }
}

// ---------------------------------------------------------------------------
// bf16 GEMM, C[M,N] = A[M,K] * B[N,K]^T, bf16 out.  128x128 tile, BK=64,
// 256 threads = 4 waves in 2x2, each wave 64x64 via 4x4 frags of 16x16x32.
// Staging via global_load_lds(16B) with XOR seg-swizzle (seg ^= row&7).
// ---------------------------------------------------------------------------
__global__ __launch_bounds__(256) void gemm_bt(const unsigned short* __restrict__ A,
                                               const unsigned short* __restrict__ B,
                                               unsigned short* __restrict__ C,
                                               int M, int N, int K) {
    __shared__ unsigned short Al[128][64];
    __shared__ unsigned short Bl[128][64];
    const int tid  = threadIdx.x;
    const int lane = tid & 63;
    const int qd   = lane >> 4;     // quad 0..3
    const int cc   = lane & 15;
    const int wave = tid >> 6;
    const int wr   = wave >> 1, wc = wave & 1;
    const int m0   = blockIdx.y * 128, n0 = blockIdx.x * 128;
    unsigned short* Alf = &Al[0][0];
    unsigned short* Blf = &Bl[0][0];

    f32x4 acc[4][4];
#pragma unroll
    for (int i = 0; i < 4; i++)
#pragma unroll
        for (int j = 0; j < 4; j++) acc[i][j] = (f32x4){0.f, 0.f, 0.f, 0.f};

    for (int k0 = 0; k0 < K; k0 += 64) {
#pragma unroll
        for (int t = 0; t < 4; t++) {
            int idx = t * 256 + tid;                 // 0..1023
            int row = idx >> 3, sg = (idx & 7) ^ (row & 7);
            GLD_TO_LDS(A + (size_t)(m0 + row) * K + k0 + sg * 8, Alf + idx * 8);
            GLD_TO_LDS(B + (size_t)(n0 + row) * K + k0 + sg * 8, Blf + idx * 8);
        }
        __syncthreads();
#pragma unroll
        for (int ks = 0; ks < 64; ks += 32) {
            const int s4 = ks >> 3;                  // 0 or 4
            s16x8 af[4], bf[4];
#pragma unroll
            for (int i = 0; i < 4; i++) {
                int r = wr * 64 + i * 16 + cc;
                af[i] = *(const s16x8*)&Al[r][((s4 + qd) ^ (r & 7)) * 8];
            }
#pragma unroll
            for (int j = 0; j < 4; j++) {
                int r = wc * 64 + j * 16 + cc;
                bf[j] = *(const s16x8*)&Bl[r][((s4 + qd) ^ (r & 7)) * 8];
            }
#pragma unroll
            for (int i = 0; i < 4; i++)
#pragma unroll
                for (int j = 0; j < 4; j++)
                    acc[i][j] = MFMA_BF16(af[i], bf[j], acc[i][j]);
        }
        __syncthreads();
    }
    // epilogue: C/D layout col=lane&15, row=quad*4+reg
#pragma unroll
    for (int i = 0; i < 4; i++)
#pragma unroll
        for (int j = 0; j < 4; j++)
#pragma unroll
            for (int r = 0; r < 4; r++) {
                int row = m0 + wr * 64 + i * 16 + qd * 4 + r;
                int col = n0 + wc * 64 + j * 16 + cc;
                C[(size_t)row * N + col] = f2bf(acc[i][j][r]);
            }
}

// ---------------------------------------------------------------------------
// RoPE + scatter: qkv[4096,3072] bf16 -> Q[B,H,N,D] (scaled by SCL), K (RoPE'd),
// V transposed -> Vt[B,H,D,N] with masked-key rows zeroed.
// One block per (b,h,64-row tile).  All global stores dense u16x8.
// ---------------------------------------------------------------------------
__global__ __launch_bounds__(256) void rope_scatter(const unsigned short* __restrict__ qkv,
                                                    const int* __restrict__ msk,
                                                    unsigned short* __restrict__ Q,
                                                    unsigned short* __restrict__ Kg,
                                                    unsigned short* __restrict__ Vt) {
    const int N = 2048, H = 16, D = 64, C3 = 3072;
    const float SCL = 0.18033688f;              // 0.125 * log2(e), folded into Q
    __shared__ unsigned short vl[64][65];       // +1 pad for transpose reads
    const int nt = blockIdx.x, h = blockIdx.y, b = blockIdx.z;
    const int n0 = nt * 64;
    const int tid = threadIdx.x;
    const size_t bh = (size_t)b * H + h;
#pragma unroll
    for (int it = 0; it < 2; it++) {
        int idx = tid + it * 256;           // 0..511
        int row = idx >> 3, seg = idx & 7;
        int d0 = seg * 8;
        int n = n0 + row;
        size_t rb = ((size_t)b * N + n) * C3;
        int keep = msk[(size_t)b * N + n];
        u16x8 qv = *(const u16x8*)&qkv[rb + h * 64 + d0];
        u16x8 qp = *(const u16x8*)&qkv[rb + h * 64 + (d0 ^ 32)];
        u16x8 kv = *(const u16x8*)&qkv[rb + 1024 + h * 64 + d0];
        u16x8 kp = *(const u16x8*)&qkv[rb + 1024 + h * 64 + (d0 ^ 32)];
        u16x8 vv = *(const u16x8*)&qkv[rb + 2048 + h * 64 + d0];
        u16x8 qo, ko;
        float sgn = (d0 < 32) ? -1.0f : 1.0f;   // rotate_half sign
#pragma unroll
        for (int j = 0; j < 8; j++) {
            int jj = (d0 & 31) + j;                              // freq index
            float th = (float)n * exp2f(-0.34375f * (float)jj);  // 2048^(-jj/32)
            float cth = cosf(th), sth = sinf(th);
            qo[j] = f2bf((bf2f(qv[j]) * cth + sgn * bf2f(qp[j]) * sth) * SCL);
            ko[j] = f2bf(bf2f(kv[j]) * cth + sgn * bf2f(kp[j]) * sth);
            vl[row][d0 + j] = keep ? vv[j] : (unsigned short)0;
        }
        *(u16x8*)&Q[(bh * N + n) * D + d0]  = qo;
        *(u16x8*)&Kg[(bh * N + n) * D + d0] = ko;
    }
    __syncthreads();
    // transposed V write: Vt[b,h,d,n]
#pragma unroll
    for (int it = 0; it < 2; it++) {
        int idx = tid + it * 256;
        int drow = idx >> 3, nseg = idx & 7;
        u16x8 ov;
#pragma unroll
        for (int j = 0; j < 8; j++) ov[j] = vl[nseg * 8 + j][drow];
        *(u16x8*)&Vt[(bh * D + drow) * N + n0 + nseg * 8] = ov;
    }
}

// ---------------------------------------------------------------------------
// Flash attention: double-buffered DMA staging of K AND V, S^T orientation,
// softmax-lite (no running max), l via MFMA-with-mask (handles key padding),
// pure exp2 inner loop (SCL pre-folded into Q, masked V rows pre-zeroed).
// R9: 512 threads = 8 waves x 16 q-rows (was 4 x 32); q-tile stays 128,
// LDS/grid unchanged -> 16 waves/CU (4/SIMD) for VALU/MFMA cross-wave overlap.
// Tile body: QK^T(all) -> sm(0,1) -> PV(ks0) -> sm(2,3) -> PV(ks1).
// ---------------------------------------------------------------------------
__global__ __launch_bounds__(512, 4) void flash_attn(const unsigned short* __restrict__ Q,
                                                     const unsigned short* __restrict__ Kg,
                                                     const unsigned short* __restrict__ Vt,
                                                     const unsigned short* __restrict__ mb,
                                                     unsigned short* __restrict__ Og) {
    const int N = 2048, H = 16, D = 64;
    __shared__ unsigned short Kl0[64][64], Kl1[64][64];   // [key][d] swizzled
    __shared__ unsigned short Vl0[64][64], Vl1[64][64];   // [d][key] swizzled
    __shared__ unsigned short Pl[8][16][76];   // [wave][query][key], stride 76
    const int tid  = threadIdx.x;
    const int lane = tid & 63;
    const int wave = tid >> 6;                 // 0..7
    const int qd   = lane >> 4;
    const int cc   = lane & 15;
    const int qt = blockIdx.x, h = blockIdx.y, b = blockIdx.z;
    const int q0 = qt * 128;
    const size_t bh = (size_t)b * H + h;

    // Q B-frags: B[n=q=lane&15][k=d=quad*8+j]  (Q already scaled by SCL)
    s16x8 qf[2];
    {
        const unsigned short* Qb = Q + (bh * N + q0 + wave * 16 + cc) * D;
        qf[0] = *(const s16x8*)(Qb + qd * 8);
        qf[1] = *(const s16x8*)(Qb + 32 + qd * 8);
    }

    f32x4 o[4], lacc = (f32x4){0.f, 0.f, 0.f, 0.f};
#pragma unroll
    for (int db = 0; db < 4; db++) o[db] = (f32x4){0.f, 0.f, 0.f, 0.f};

    const unsigned short* Kbase = Kg + bh * N * D;
    const unsigned short* Vbase = Vt + bh * D * N;
    const unsigned short* mbase = mb + (size_t)b * N;   // bf16 0/1 mask vector
    const int row_s = tid >> 3, sg_s = (tid & 7) ^ ((tid >> 3) & 7);  // 512 thr cover 64x64

    auto issue = [&](int k0, unsigned short* Kb, unsigned short* Vb) {
        GLD_TO_LDS(Kbase + (size_t)(k0 + row_s) * D + sg_s * 8, Kb + tid * 8);
        GLD_TO_LDS(Vbase + (size_t)row_s * N + k0 + sg_s * 8,   Vb + tid * 8);
    };

    auto compute = [&](int k0, const unsigned short (*Kb)[64], const unsigned short (*Vb)[64]) {
        // mask B-frags for both key-halves, issued before the MFMA cluster
        s16x8 mf0 = *(const s16x8*)&mbase[k0 + qd * 8];
        s16x8 mf1 = *(const s16x8*)&mbase[k0 + 32 + qd * 8];

        // ---- QK^T: all 4 key-subtiles into registers --------------------
        f32x4 sst[4];
        __builtin_amdgcn_s_setprio(1);
#pragma unroll
        for (int sub = 0; sub < 4; sub++) {
            int kr = sub * 16 + cc;
            s16x8 kf0 = *(const s16x8*)&Kb[kr][((0 + qd) ^ (kr & 7)) * 8];
            s16x8 kf1 = *(const s16x8*)&Kb[kr][((4 + qd) ^ (kr & 7)) * 8];
            f32x4 s = (f32x4){0.f, 0.f, 0.f, 0.f};
            s = MFMA_BF16(kf0, qf[0], s);
            sst[sub] = MFMA_BF16(kf1, qf[1], s);
        }
        __builtin_amdgcn_s_setprio(0);

        // ---- softmax-lite for one 16-key subtile: p = exp2(s), pack -> Pl
        auto sm = [&](int sub) {
            f32x4 s = sst[sub];
            float p0 = exp2f(s[0]);
            float p1 = exp2f(s[1]);
            float p2 = exp2f(s[2]);
            float p3 = exp2f(s[3]);
            unsigned int w0 = __builtin_amdgcn_perm(
                __builtin_bit_cast(unsigned int, p1),
                __builtin_bit_cast(unsigned int, p0), 0x07060302u);
            unsigned int w1 = __builtin_amdgcn_perm(
                __builtin_bit_cast(unsigned int, p3),
                __builtin_bit_cast(unsigned int, p2), 0x07060302u);
            unsigned long long w = ((unsigned long long)w1 << 32) | w0;
            *(unsigned long long*)&Pl[wave][cc][sub * 16 + qd * 4] = w;
        };

        // ---- O += P V ; l += P @ mask, for one 32-key half --------------
        auto pv = [&](int ks, s16x8 mf) {
            s16x8 vfl[4];
#pragma unroll
            for (int db = 0; db < 4; db++) {
                int vr = db * 16 + cc;
                vfl[db] = *(const s16x8*)&Vb[vr][((ks * 4 + qd) ^ (vr & 7)) * 8];
            }
            s16x8 pf = *(const s16x8*)&Pl[wave][cc][ks * 32 + qd * 8];
            __builtin_amdgcn_s_setprio(1);
            lacc = MFMA_BF16(pf, mf, lacc);
#pragma unroll
            for (int db = 0; db < 4; db++)
                o[db] = MFMA_BF16(pf, vfl[db], o[db]);
            __builtin_amdgcn_s_setprio(0);
        };

        sm(0); sm(1);     // keys 0..31 ready (overlaps S-MFMA latency of subs 2,3)
        pv(0, mf0);       // PV on keys 0..31
        sm(2); sm(3);     // keys 32..63 exp/pack overlap PV(ks=0) MFMA latency
        pv(1, mf1);       // PV on keys 32..63
    };

    issue(0, &Kl0[0][0], &Vl0[0][0]);
    __syncthreads();
    for (int it = 0; it < 32; it += 2) {
        int k0 = it * 64;
        if (it + 1 < 32) issue(k0 + 64, &Kl1[0][0], &Vl1[0][0]);
        compute(k0, Kl0, Vl0);
        __syncthreads();
        if (it + 2 < 32) issue(k0 + 128, &Kl0[0][0], &Vl0[0][0]);
        compute(k0 + 64, Kl1, Vl1);
        __syncthreads();
    }

    // epilogue: lacc rows == o rows (query = wave*16 + qd*4 + r)
    float linv[4];
#pragma unroll
    for (int r = 0; r < 4; r++) linv[r] = 1.0f / lacc[r];
#pragma unroll
    for (int db = 0; db < 4; db++)
#pragma unroll
        for (int r = 0; r < 4; r++) {
            int n = q0 + wave * 16 + qd * 4 + r;
            Og[((size_t)b * N + n) * 1024 + h * 64 + db * 16 + cc] =
                f2bf(o[db][r] * linv[r]);
        }
}

// ---------------------------------------------------------------------------
// Projection GEMM: out[4096,1024] = attno[4096,1024] @ w_proj^T + bias, fp32.
// 128x64 tile -> 512 blocks = 2 blocks/CU.
// ---------------------------------------------------------------------------
__global__ __launch_bounds__(256) void gemm_proj(const unsigned short* __restrict__ A,
                                                 const unsigned short* __restrict__ B,
                                                 float* __restrict__ C,
                                                 const float* __restrict__ bias) {
    const int NN = 1024, K = 1024;
    __shared__ unsigned short Al[128][64];
    __shared__ unsigned short Bl[64][64];
    const int tid  = threadIdx.x;
    const int lane = tid & 63;
    const int qd   = lane >> 4;
    const int cc   = lane & 15;
    const int wave = tid >> 6;
    const int wr   = wave >> 1, wc = wave & 1;
    const int m0   = blockIdx.y * 128, n0 = blockIdx.x * 64;
    unsigned short* Alf = &Al[0][0];
    unsigned short* Blf = &Bl[0][0];

    f32x4 acc[4][2];
#pragma unroll
    for (int i = 0; i < 4; i++)
#pragma unroll
        for (int j = 0; j < 2; j++) acc[i][j] = (f32x4){0.f, 0.f, 0.f, 0.f};

    for (int k0 = 0; k0 < K; k0 += 64) {
#pragma unroll
        for (int t = 0; t < 4; t++) {
            int idx = t * 256 + tid;
            int row = idx >> 3, sg = (idx & 7) ^ (row & 7);
            GLD_TO_LDS(A + (size_t)(m0 + row) * K + k0 + sg * 8, Alf + idx * 8);
        }
#pragma unroll
        for (int t = 0; t < 2; t++) {
            int idx = t * 256 + tid;
            int row = idx >> 3, sg = (idx & 7) ^ (row & 7);
            GLD_TO_LDS(B + (size_t)(n0 + row) * K + k0 + sg * 8, Blf + idx * 8);
        }
        __syncthreads();
#pragma unroll
        for (int ks = 0; ks < 64; ks += 32) {
            const int s4 = ks >> 3;
            s16x8 af[4], bf[2];
#pragma unroll
            for (int i = 0; i < 4; i++) {
                int r = wr * 64 + i * 16 + cc;
                af[i] = *(const s16x8*)&Al[r][((s4 + qd) ^ (r & 7)) * 8];
            }
#pragma unroll
            for (int j = 0; j < 2; j++) {
                int r = wc * 32 + j * 16 + cc;
                bf[j] = *(const s16x8*)&Bl[r][((s4 + qd) ^ (r & 7)) * 8];
            }
#pragma unroll
            for (int i = 0; i < 4; i++)
#pragma unroll
                for (int j = 0; j < 2; j++)
                    acc[i][j] = MFMA_BF16(af[i], bf[j], acc[i][j]);
        }
        __syncthreads();
    }
#pragma unroll
    for (int i = 0; i < 4; i++)
#pragma unroll
        for (int j = 0; j < 2; j++)
#pragma unroll
            for (int r = 0; r < 4; r++) {
                int row = m0 + wr * 64 + i * 16 + qd * 4 + r;
                int col = n0 + wc * 32 + j * 16 + cc;
                C[(size_t)row * NN + col] = acc[i][j][r] + bias[col];
            }
}

// ---------------------------------------------------------------------------
extern "C" void kernel_launch(void* const* d_in, const int* in_sizes, int n_in,
                              void* d_out, int out_size, void* d_ws, size_t ws_size,
                              hipStream_t stream) {
    const float* x      = (const float*)d_in[0];
    const float* w_qkv  = (const float*)d_in[1];
    const float* w_proj = (const float*)d_in[2];
    const float* b_proj = (const float*)d_in[3];
    const int*   mask   = (const int*)d_in[4];
    float* out = (float*)d_out;

    // workspace layout (bf16 elements), ~72 MB
    unsigned short* ws     = (unsigned short*)d_ws;
    unsigned short* xb     = ws;                                  // 4096*1024
    unsigned short* wqkvb  = xb     + (size_t)4096 * 1024;        // 3072*1024
    unsigned short* wprojb = wqkvb  + (size_t)3072 * 1024;        // 1024*1024
    unsigned short* qkv    = wprojb + (size_t)1024 * 1024;        // 4096*3072
    unsigned short* Qm     = qkv    + (size_t)4096 * 3072;        // 32*2048*64
    unsigned short* Km     = Qm     + (size_t)32 * 2048 * 64;
    unsigned short* Vtm    = Km     + (size_t)32 * 2048 * 64;
    unsigned short* attno  = Vtm    + (size_t)32 * 2048 * 64;     // 4096*1024
    unsigned short* maskbf = attno  + (size_t)4096 * 1024;        // 2*2048 bf16

    // converts + bf16 mask vector, one launch
    prep<<<8208, 256, 0, stream>>>(x, w_qkv, w_proj, mask, xb, wqkvb, wprojb, maskbf);
    // qkv = x @ w_qkv^T   [4096, 3072]
    gemm_bt<<<dim3(24, 32), 256, 0, stream>>>(xb, wqkvb, qkv, 4096, 3072, 1024);
    // RoPE + scatter to Q (SCL-scaled) / K [B,H,N,D] and Vt [B,H,D,N] (masked rows zeroed)
    rope_scatter<<<dim3(32, 16, 2), 256, 0, stream>>>(qkv, mask, Qm, Km, Vtm);
    // attention: 128-row Q tiles, 8 waves x 16 q-rows, double-buffered staging
    flash_attn<<<dim3(16, 16, 2), 512, 0, stream>>>(Qm, Km, Vtm, maskbf, attno);
    // out = attn_out @ w_proj^T + b_proj
    gemm_proj<<<dim3(16, 32), 256, 0, stream>>>(attno, wprojb, out, b_proj);
}

// Round 6
// 189.414 us; speedup vs baseline: 1.0888x; 1.0528x over previous
//
#include <hip/hip_runtime.h>

// ---------------------------------------------------------------------------
// Fused attention: x@Wqkv^T -> RoPE -> masked softmax attention -> @Wproj^T+b
// B=2, N=2048, C=1024, H=16, D=64.  All MFMA compute in bf16, fp32 accum.
//
// LESSON (R5): no scalar 2B global stores (16x HBM write amplification).
// LESSON (R9): per-wave K/V LDS fragment reads are fixed overhead independent
// of q-rows/wave; 8w x 16q doubled LDS traffic and ate the occupancy win.
// LESSON (R10): v_permlane32_swap_b32 swap-direction semantics are NOT
// verified anywhere in our stack; using it scrambled the P<->V key pairing
// (absmax 0.32).  Avoid unverified cross-lane primitives entirely.
//
// R11: same 32x32x16 / 4 waves x 32 q-rows / in-register-P structure as R10,
// but the PV A-frag is a DIRECT pack of the QK^T C/D registers (keys land in
// order perm16[p] = (p&3)+8*((p>>2)&1)+4*(p>>3) per 16-key slice), and V and
// the mask vector are PRE-PERMUTED by perm16 (an involution) at scatter/prep
// time so B-frag element (hi,j) carries the same key as A element (hi,j).
// MFMA pairs A(hi,j) with B(hi,j) (operand symmetry confirmed by the working
// 16x16 kernel), so no cross-lane exchange is needed at all.
// ---------------------------------------------------------------------------

typedef __attribute__((ext_vector_type(8))) short          s16x8;
typedef __attribute__((ext_vector_type(8))) unsigned short u16x8;
typedef __attribute__((ext_vector_type(4))) unsigned short u16x4;
typedef __attribute__((ext_vector_type(4))) float          f32x4;
typedef __attribute__((ext_vector_type(16))) float         f32x16;
typedef __attribute__((ext_vector_type(4))) unsigned int   u32x4;

#define MFMA_BF16(a, b, c) __builtin_amdgcn_mfma_f32_16x16x32_bf16((a), (b), (c), 0, 0, 0)
#define MFMA32_BF16(a, b, c) __builtin_amdgcn_mfma_f32_32x32x16_bf16((a), (b), (c), 0, 0, 0)

// async global->LDS, 16B per lane (dest = wave-uniform base + lane*16)
#define GLD_TO_LDS(gp, lp) __builtin_amdgcn_global_load_lds(                  \
    (const __attribute__((address_space(1))) void*)(gp),                      \
    (__attribute__((address_space(3))) void*)(lp), 16, 0, 0)

__device__ __forceinline__ unsigned short f2bf(float f) {
    union { float f; unsigned int u; } v; v.f = f;
    unsigned int u = v.u;
    unsigned int r = u + 0x7FFFu + ((u >> 16) & 1u);   // round-to-nearest-even
    return (unsigned short)(r >> 16);
}
__device__ __forceinline__ float bf2f(unsigned short h) {
    union { unsigned int u; float f; } v; v.u = ((unsigned int)h) << 16;
    return v.f;
}
__device__ __forceinline__ f32x16 zero16() {
    f32x16 z;
#pragma unroll
    for (int i = 0; i < 16; i++) z[i] = 0.f;
    return z;
}
// pack two f32 -> one u32 of 2 bf16 (truncating): low half = a, high = b
__device__ __forceinline__ unsigned int pkbf(float a, float b) {
    return __builtin_amdgcn_perm(__builtin_bit_cast(unsigned int, b),
                                 __builtin_bit_cast(unsigned int, a), 0x07060302u);
}
// key permutation within a 16-block matching the 32x32 C/D row map
// (involution: swaps 4..7 <-> 8..11)
__device__ __forceinline__ int perm16(int p) {
    return (p & 3) + 8 * ((p >> 2) & 1) + 4 * (p >> 3);
}

// ---------------------------------------------------------------------------
// prep: fp32->bf16 converts for x, w_qkv, w_proj + mask -> bf16 0/1 vector
// stored PERM16-PERMUTED within each 16-key block (for flash's lacc B-frag).
// ---------------------------------------------------------------------------
__global__ __launch_bounds__(256) void prep(const float* __restrict__ x,
                                            const float* __restrict__ wqkv,
                                            const float* __restrict__ wproj,
                                            const int* __restrict__ m,
                                            unsigned short* __restrict__ xb,
                                            unsigned short* __restrict__ wqkvb,
                                            unsigned short* __restrict__ wprojb,
                                            unsigned short* __restrict__ mb) {
    int blk = blockIdx.x, tid = threadIdx.x;
    if (blk < 8192) {
        const float* src; unsigned short* dst; int i;
        if (blk < 4096)      { src = x;     dst = xb;     i = blk * 256 + tid; }
        else if (blk < 7168) { src = wqkv;  dst = wqkvb;  i = (blk - 4096) * 256 + tid; }
        else                 { src = wproj; dst = wprojb; i = (blk - 7168) * 256 + tid; }
        f32x4 v = ((const f32x4*)src)[i];
        u16x4 o;
        o[0] = f2bf(v[0]); o[1] = f2bf(v[1]); o[2] = f2bf(v[2]); o[3] = f2bf(v[3]);
        ((u16x4*)dst)[i] = o;
    } else {
        int i = (blk - 8192) * 256 + tid;
        int src = (i & ~15) | perm16(i & 15);          // N=2048 % 16 == 0: stays in batch
        mb[i] = (m[src] == 0) ? (unsigned short)0 : (unsigned short)0x3F80;  // bf16 1.0
    }
}

// ---------------------------------------------------------------------------
// bf16 GEMM, C[M,N] = A[M,K] * B[N,K]^T, bf16 out.  128x128 tile, BK=64.
// ---------------------------------------------------------------------------
__global__ __launch_bounds__(256) void gemm_bt(const unsigned short* __restrict__ A,
                                               const unsigned short* __restrict__ B,
                                               unsigned short* __restrict__ C,
                                               int M, int N, int K) {
    __shared__ unsigned short Al[128][64];
    __shared__ unsigned short Bl[128][64];
    const int tid  = threadIdx.x;
    const int lane = tid & 63;
    const int qd   = lane >> 4;     // quad 0..3
    const int cc   = lane & 15;
    const int wave = tid >> 6;
    const int wr   = wave >> 1, wc = wave & 1;
    const int m0   = blockIdx.y * 128, n0 = blockIdx.x * 128;
    unsigned short* Alf = &Al[0][0];
    unsigned short* Blf = &Bl[0][0];

    f32x4 acc[4][4];
#pragma unroll
    for (int i = 0; i < 4; i++)
#pragma unroll
        for (int j = 0; j < 4; j++) acc[i][j] = (f32x4){0.f, 0.f, 0.f, 0.f};

    for (int k0 = 0; k0 < K; k0 += 64) {
#pragma unroll
        for (int t = 0; t < 4; t++) {
            int idx = t * 256 + tid;                 // 0..1023
            int row = idx >> 3, sg = (idx & 7) ^ (row & 7);
            GLD_TO_LDS(A + (size_t)(m0 + row) * K + k0 + sg * 8, Alf + idx * 8);
            GLD_TO_LDS(B + (size_t)(n0 + row) * K + k0 + sg * 8, Blf + idx * 8);
        }
        __syncthreads();
#pragma unroll
        for (int ks = 0; ks < 64; ks += 32) {
            const int s4 = ks >> 3;                  // 0 or 4
            s16x8 af[4], bf[4];
#pragma unroll
            for (int i = 0; i < 4; i++) {
                int r = wr * 64 + i * 16 + cc;
                af[i] = *(const s16x8*)&Al[r][((s4 + qd) ^ (r & 7)) * 8];
            }
#pragma unroll
            for (int j = 0; j < 4; j++) {
                int r = wc * 64 + j * 16 + cc;
                bf[j] = *(const s16x8*)&Bl[r][((s4 + qd) ^ (r & 7)) * 8];
            }
#pragma unroll
            for (int i = 0; i < 4; i++)
#pragma unroll
                for (int j = 0; j < 4; j++)
                    acc[i][j] = MFMA_BF16(af[i], bf[j], acc[i][j]);
        }
        __syncthreads();
    }
    // epilogue: C/D layout col=lane&15, row=quad*4+reg
#pragma unroll
    for (int i = 0; i < 4; i++)
#pragma unroll
        for (int j = 0; j < 4; j++)
#pragma unroll
            for (int r = 0; r < 4; r++) {
                int row = m0 + wr * 64 + i * 16 + qd * 4 + r;
                int col = n0 + wc * 64 + j * 16 + cc;
                C[(size_t)row * N + col] = f2bf(acc[i][j][r]);
            }
}

// ---------------------------------------------------------------------------
// RoPE + scatter: qkv[4096,3072] bf16 -> Q[B,H,N,D] (scaled by SCL), K (RoPE'd),
// V transposed -> Vt[B,H,D,N] with masked-key rows zeroed AND the key axis
// perm16-permuted within each 16-key block (flash PV B-frag order).
// ---------------------------------------------------------------------------
__global__ __launch_bounds__(256) void rope_scatter(const unsigned short* __restrict__ qkv,
                                                    const int* __restrict__ msk,
                                                    unsigned short* __restrict__ Q,
                                                    unsigned short* __restrict__ Kg,
                                                    unsigned short* __restrict__ Vt) {
    const int N = 2048, H = 16, D = 64, C3 = 3072;
    const float SCL = 0.18033688f;              // 0.125 * log2(e), folded into Q
    __shared__ unsigned short vl[64][65];       // +1 pad for transpose reads
    const int nt = blockIdx.x, h = blockIdx.y, b = blockIdx.z;
    const int n0 = nt * 64;
    const int tid = threadIdx.x;
    const size_t bh = (size_t)b * H + h;
#pragma unroll
    for (int it = 0; it < 2; it++) {
        int idx = tid + it * 256;           // 0..511
        int row = idx >> 3, seg = idx & 7;
        int d0 = seg * 8;
        int n = n0 + row;
        size_t rb = ((size_t)b * N + n) * C3;
        int keep = msk[(size_t)b * N + n];
        u16x8 qv = *(const u16x8*)&qkv[rb + h * 64 + d0];
        u16x8 qp = *(const u16x8*)&qkv[rb + h * 64 + (d0 ^ 32)];
        u16x8 kv = *(const u16x8*)&qkv[rb + 1024 + h * 64 + d0];
        u16x8 kp = *(const u16x8*)&qkv[rb + 1024 + h * 64 + (d0 ^ 32)];
        u16x8 vv = *(const u16x8*)&qkv[rb + 2048 + h * 64 + d0];
        u16x8 qo, ko;
        float sgn = (d0 < 32) ? -1.0f : 1.0f;   // rotate_half sign
#pragma unroll
        for (int j = 0; j < 8; j++) {
            int jj = (d0 & 31) + j;                              // freq index
            float th = (float)n * exp2f(-0.34375f * (float)jj);  // 2048^(-jj/32)
            float cth = cosf(th), sth = sinf(th);
            qo[j] = f2bf((bf2f(qv[j]) * cth + sgn * bf2f(qp[j]) * sth) * SCL);
            ko[j] = f2bf(bf2f(kv[j]) * cth + sgn * bf2f(kp[j]) * sth);
            vl[row][d0 + j] = keep ? vv[j] : (unsigned short)0;
        }
        *(u16x8*)&Q[(bh * N + n) * D + d0]  = qo;
        *(u16x8*)&Kg[(bh * N + n) * D + d0] = ko;
    }
    __syncthreads();
    // transposed V write: Vt[b,h,d, n-permuted]: Vt[.., 16t+p] = V[16t+perm16(p)]
#pragma unroll
    for (int it = 0; it < 2; it++) {
        int idx = tid + it * 256;
        int drow = idx >> 3, nseg = idx & 7;
        u16x8 ov;
#pragma unroll
        for (int j = 0; j < 8; j++) {
            int cpos = nseg * 8 + j;
            int srcl = (cpos & ~15) | perm16(cpos & 15);
            ov[j] = vl[srcl][drow];
        }
        *(u16x8*)&Vt[(bh * D + drow) * N + n0 + nseg * 8] = ov;
    }
}

// ---------------------------------------------------------------------------
// Flash attention R11: 32x32x16 MFMA, 4 waves x 32 q-rows, in-register P.
// S^T = mfma32(K, Q): lane holds P[q=lane&31][key=kg*32+(r&3)+8(r>>2)+4*hi].
// PV A-frag = DIRECT pack of p[0..7] / p[8..15]; V and mask are perm16-
// pre-permuted so B element (hi,j) carries the same key.  No P LDS, no
// cross-lane ops.  l = P @ mask via mfma32.  Double-buffered K/V staging.
// ---------------------------------------------------------------------------
__global__ __launch_bounds__(256, 2) void flash_attn(const unsigned short* __restrict__ Q,
                                                     const unsigned short* __restrict__ Kg,
                                                     const unsigned short* __restrict__ Vt,
                                                     const unsigned short* __restrict__ mb,
                                                     unsigned short* __restrict__ Og) {
    const int N = 2048, H = 16, D = 64;
    __shared__ unsigned short Kl0[64][64], Kl1[64][64];   // [key][d] swizzled
    __shared__ unsigned short Vl0[64][64], Vl1[64][64];   // [d][key-perm] swizzled
    const int tid  = threadIdx.x;
    const int lane = tid & 63;
    const int wave = tid >> 6;                 // 0..3
    const int c    = lane & 31;                // q (and K-row / V-row) index
    const int hi   = lane >> 5;                // 0/1: k-half of fragments
    const int qt = blockIdx.x, h = blockIdx.y, b = blockIdx.z;
    const int q0 = qt * 128;
    const size_t bh = (size_t)b * H + h;

    // Q B-frags: B[n=q=lane&31][k=d=kd*16+hi*8+j]  (Q already scaled by SCL)
    s16x8 qf[4];
    {
        const unsigned short* Qb = Q + (bh * N + q0 + wave * 32 + c) * D;
#pragma unroll
        for (int kd = 0; kd < 4; kd++) qf[kd] = *(const s16x8*)(Qb + kd * 16 + hi * 8);
    }

    f32x16 o[2], lacc;
    o[0] = zero16(); o[1] = zero16(); lacc = zero16();

    const unsigned short* Kbase = Kg + bh * N * D;
    const unsigned short* Vbase = Vt + bh * D * N;
    const unsigned short* mbase = mb + (size_t)b * N;   // perm16'd bf16 0/1 mask
    const int row_s = tid >> 3, sg_s = (tid & 7) ^ ((tid >> 3) & 7);
    const int row_s2 = (tid + 256) >> 3, sg_s2 = (tid & 7) ^ (((tid + 256) >> 3) & 7);

    auto issue = [&](int k0, unsigned short* Kb, unsigned short* Vb) {
        GLD_TO_LDS(Kbase + (size_t)(k0 + row_s) * D + sg_s * 8,   Kb + tid * 8);
        GLD_TO_LDS(Vbase + (size_t)row_s * N + k0 + sg_s * 8,     Vb + tid * 8);
        GLD_TO_LDS(Kbase + (size_t)(k0 + row_s2) * D + sg_s2 * 8, Kb + (tid + 256) * 8);
        GLD_TO_LDS(Vbase + (size_t)row_s2 * N + k0 + sg_s2 * 8,   Vb + (tid + 256) * 8);
    };

    auto compute = [&](int k0, const unsigned short (*Kb)[64], const unsigned short (*Vb)[64]) {
        // ---- QK^T: S^T[kg] = K[kg] x Q over D=64 (4 k-slices) ------------
        f32x16 sst[2];
        __builtin_amdgcn_s_setprio(1);
#pragma unroll
        for (int kg = 0; kg < 2; kg++) {
            int kr = kg * 32 + c;
            f32x16 s = zero16();
#pragma unroll
            for (int kd = 0; kd < 4; kd++) {
                s16x8 kf = *(const s16x8*)&Kb[kr][((kd * 2 + hi) ^ (kr & 7)) * 8];
                s = MFMA32_BF16(kf, qf[kd], s);
            }
            sst[kg] = s;
        }
        __builtin_amdgcn_s_setprio(0);

        // ---- exp2 + DIRECT in-register pack -> two PV A-frags per kg -----
        // p[r] holds key kg*32+(r&3)+8(r>>2)+4hi; A element j of pa[half]
        // carries key kg*32+half*16+perm16(hi*8+j) — matching pre-permuted V.
        auto packkg = [&](int kg, s16x8* pa) {
            float p[16];
#pragma unroll
            for (int r = 0; r < 16; r++) p[r] = __builtin_amdgcn_exp2f(sst[kg][r]);
#pragma unroll
            for (int half = 0; half < 2; half++) {
                int bs = half * 8;
                u32x4 w = { pkbf(p[bs + 0], p[bs + 1]), pkbf(p[bs + 2], p[bs + 3]),
                            pkbf(p[bs + 4], p[bs + 5]), pkbf(p[bs + 6], p[bs + 7]) };
                pa[half] = __builtin_bit_cast(s16x8, w);
            }
        };

        // ---- O += P V ; l += P @ mask for one 16-key slice ---------------
        auto pvks = [&](int ks, s16x8 pf) {
            s16x8 mfr = *(const s16x8*)&mbase[k0 + ks * 16 + hi * 8];
            __builtin_amdgcn_s_setprio(1);
            lacc = MFMA32_BF16(pf, mfr, lacc);
#pragma unroll
            for (int db = 0; db < 2; db++) {
                int vr = db * 32 + c;
                s16x8 vf = *(const s16x8*)&Vb[vr][((ks * 2 + hi) ^ (vr & 7)) * 8];
                o[db] = MFMA32_BF16(pf, vf, o[db]);
            }
            __builtin_amdgcn_s_setprio(0);
        };

        s16x8 pa[2];
        packkg(0, pa);            // keys 0..31 (overlaps kg=1 S-MFMA latency)
        pvks(0, pa[0]);
        pvks(1, pa[1]);
        packkg(1, pa);            // keys 32..63 overlap PV MFMA latency
        pvks(2, pa[0]);
        pvks(3, pa[1]);
    };

    issue(0, &Kl0[0][0], &Vl0[0][0]);
    __syncthreads();
    for (int it = 0; it < 32; it += 2) {
        int k0 = it * 64;
        if (it + 1 < 32) issue(k0 + 64, &Kl1[0][0], &Vl1[0][0]);
        compute(k0, Kl0, Vl0);
        __syncthreads();
        if (it + 2 < 32) issue(k0 + 128, &Kl0[0][0], &Vl0[0][0]);
        compute(k0 + 64, Kl1, Vl1);
        __syncthreads();
    }

    // epilogue: row q = q0 + wave*32 + (r&3)+8*(r>>2)+4*hi; col d = db*32 + c
    float linv[16];
#pragma unroll
    for (int r = 0; r < 16; r++) linv[r] = 1.0f / lacc[r];
#pragma unroll
    for (int db = 0; db < 2; db++)
#pragma unroll
        for (int r = 0; r < 16; r++) {
            int n = q0 + wave * 32 + (r & 3) + 8 * (r >> 2) + 4 * hi;
            Og[((size_t)b * N + n) * 1024 + h * 64 + db * 32 + c] =
                f2bf(o[db][r] * linv[r]);
        }
}

// ---------------------------------------------------------------------------
// Projection GEMM: out[4096,1024] = attno[4096,1024] @ w_proj^T + bias, fp32.
// ---------------------------------------------------------------------------
__global__ __launch_bounds__(256) void gemm_proj(const unsigned short* __restrict__ A,
                                                 const unsigned short* __restrict__ B,
                                                 float* __restrict__ C,
                                                 const float* __restrict__ bias) {
    const int NN = 1024, K = 1024;
    __shared__ unsigned short Al[128][64];
    __shared__ unsigned short Bl[64][64];
    const int tid  = threadIdx.x;
    const int lane = tid & 63;
    const int qd   = lane >> 4;
    const int cc   = lane & 15;
    const int wave = tid >> 6;
    const int wr   = wave >> 1, wc = wave & 1;
    const int m0   = blockIdx.y * 128, n0 = blockIdx.x * 64;
    unsigned short* Alf = &Al[0][0];
    unsigned short* Blf = &Bl[0][0];

    f32x4 acc[4][2];
#pragma unroll
    for (int i = 0; i < 4; i++)
#pragma unroll
        for (int j = 0; j < 2; j++) acc[i][j] = (f32x4){0.f, 0.f, 0.f, 0.f};

    for (int k0 = 0; k0 < K; k0 += 64) {
#pragma unroll
        for (int t = 0; t < 4; t++) {
            int idx = t * 256 + tid;
            int row = idx >> 3, sg = (idx & 7) ^ (row & 7);
            GLD_TO_LDS(A + (size_t)(m0 + row) * K + k0 + sg * 8, Alf + idx * 8);
        }
#pragma unroll
        for (int t = 0; t < 2; t++) {
            int idx = t * 256 + tid;
            int row = idx >> 3, sg = (idx & 7) ^ (row & 7);
            GLD_TO_LDS(B + (size_t)(n0 + row) * K + k0 + sg * 8, Blf + idx * 8);
        }
        __syncthreads();
#pragma unroll
        for (int ks = 0; ks < 64; ks += 32) {
            const int s4 = ks >> 3;
            s16x8 af[4], bf[2];
#pragma unroll
            for (int i = 0; i < 4; i++) {
                int r = wr * 64 + i * 16 + cc;
                af[i] = *(const s16x8*)&Al[r][((s4 + qd) ^ (r & 7)) * 8];
            }
#pragma unroll
            for (int j = 0; j < 2; j++) {
                int r = wc * 32 + j * 16 + cc;
                bf[j] = *(const s16x8*)&Bl[r][((s4 + qd) ^ (r & 7)) * 8];
            }
#pragma unroll
            for (int i = 0; i < 4; i++)
#pragma unroll
                for (int j = 0; j < 2; j++)
                    acc[i][j] = MFMA_BF16(af[i], bf[j], acc[i][j]);
        }
        __syncthreads();
    }
#pragma unroll
    for (int i = 0; i < 4; i++)
#pragma unroll
        for (int j = 0; j < 2; j++)
#pragma unroll
            for (int r = 0; r < 4; r++) {
                int row = m0 + wr * 64 + i * 16 + qd * 4 + r;
                int col = n0 + wc * 32 + j * 16 + cc;
                C[(size_t)row * NN + col] = acc[i][j][r] + bias[col];
            }
}

// ---------------------------------------------------------------------------
extern "C" void kernel_launch(void* const* d_in, const int* in_sizes, int n_in,
                              void* d_out, int out_size, void* d_ws, size_t ws_size,
                              hipStream_t stream) {
    const float* x      = (const float*)d_in[0];
    const float* w_qkv  = (const float*)d_in[1];
    const float* w_proj = (const float*)d_in[2];
    const float* b_proj = (const float*)d_in[3];
    const int*   mask   = (const int*)d_in[4];
    float* out = (float*)d_out;

    // workspace layout (bf16 elements), ~72 MB
    unsigned short* ws     = (unsigned short*)d_ws;
    unsigned short* xb     = ws;                                  // 4096*1024
    unsigned short* wqkvb  = xb     + (size_t)4096 * 1024;        // 3072*1024
    unsigned short* wprojb = wqkvb  + (size_t)3072 * 1024;        // 1024*1024
    unsigned short* qkv    = wprojb + (size_t)1024 * 1024;        // 4096*3072
    unsigned short* Qm     = qkv    + (size_t)4096 * 3072;        // 32*2048*64
    unsigned short* Km     = Qm     + (size_t)32 * 2048 * 64;
    unsigned short* Vtm    = Km     + (size_t)32 * 2048 * 64;
    unsigned short* attno  = Vtm    + (size_t)32 * 2048 * 64;     // 4096*1024
    unsigned short* maskbf = attno  + (size_t)4096 * 1024;        // 2*2048 bf16

    // converts + perm16'd bf16 mask vector, one launch
    prep<<<8208, 256, 0, stream>>>(x, w_qkv, w_proj, mask, xb, wqkvb, wprojb, maskbf);
    // qkv = x @ w_qkv^T   [4096, 3072]
    gemm_bt<<<dim3(24, 32), 256, 0, stream>>>(xb, wqkvb, qkv, 4096, 3072, 1024);
    // RoPE + scatter to Q (SCL-scaled) / K [B,H,N,D]; Vt [B,H,D,N] perm16'd + masked rows zeroed
    rope_scatter<<<dim3(32, 16, 2), 256, 0, stream>>>(qkv, mask, Qm, Km, Vtm);
    // attention: 128-row Q tiles, 4 waves x 32 q-rows, 32x32 MFMA, in-reg P
    flash_attn<<<dim3(16, 16, 2), 256, 0, stream>>>(Qm, Km, Vtm, maskbf, attno);
    // out = attn_out @ w_proj^T + b_proj
    gemm_proj<<<dim3(16, 32), 256, 0, stream>>>(attno, wprojb, out, b_proj);
}

// Round 7
// 185.754 us; speedup vs baseline: 1.1103x; 1.0197x over previous
//
#include <hip/hip_runtime.h>

// ---------------------------------------------------------------------------
// Fused attention: x@Wqkv^T -> RoPE -> masked softmax attention -> @Wproj^T+b
// B=2, N=2048, C=1024, H=16, D=64.  All MFMA compute in bf16, fp32 accum.
//
// LESSON (R5): no scalar 2B global stores (16x HBM write amplification).
// LESSON (R9): per-wave K/V LDS fragment reads are fixed overhead independent
// of q-rows/wave; 8w x 16q doubled LDS traffic and ate the occupancy win.
// LESSON (R10): unverified cross-lane primitives (v_permlane32_swap_b32)
// scrambled P<->V pairing; avoided entirely via perm16 pre-permuted V/mask.
// R11 (measured): 32x32x16 + in-register P: flash 61.3 -> 52.2 us, VALUBusy
// 53 -> 25.  flash FETCH 69.7 MB vs ~25 MB compulsory: K/V re-fetched per XCD
// because same-(b,h) q-tile blocks scatter round-robin across XCDs.
//
// R12: T1 XCD-aware chunked block swizzle (swz=(d%8)*cpx+d/8, bijective) on
// flash_attn (512=8x64), gemm_bt (768=8x96), gemm_proj (512=8x64): co-locate
// blocks sharing K/V panels (flash) or A-panels (GEMMs) on one XCD's L2 ->
// fewer HBM misses -> shorter global_load_lds drains at each barrier.
// ---------------------------------------------------------------------------

typedef __attribute__((ext_vector_type(8))) short          s16x8;
typedef __attribute__((ext_vector_type(8))) unsigned short u16x8;
typedef __attribute__((ext_vector_type(4))) unsigned short u16x4;
typedef __attribute__((ext_vector_type(4))) float          f32x4;
typedef __attribute__((ext_vector_type(16))) float         f32x16;
typedef __attribute__((ext_vector_type(4))) unsigned int   u32x4;

#define MFMA_BF16(a, b, c) __builtin_amdgcn_mfma_f32_16x16x32_bf16((a), (b), (c), 0, 0, 0)
#define MFMA32_BF16(a, b, c) __builtin_amdgcn_mfma_f32_32x32x16_bf16((a), (b), (c), 0, 0, 0)

// async global->LDS, 16B per lane (dest = wave-uniform base + lane*16)
#define GLD_TO_LDS(gp, lp) __builtin_amdgcn_global_load_lds(                  \
    (const __attribute__((address_space(1))) void*)(gp),                      \
    (__attribute__((address_space(3))) void*)(lp), 16, 0, 0)

__device__ __forceinline__ unsigned short f2bf(float f) {
    union { float f; unsigned int u; } v; v.f = f;
    unsigned int u = v.u;
    unsigned int r = u + 0x7FFFu + ((u >> 16) & 1u);   // round-to-nearest-even
    return (unsigned short)(r >> 16);
}
__device__ __forceinline__ float bf2f(unsigned short h) {
    union { unsigned int u; float f; } v; v.u = ((unsigned int)h) << 16;
    return v.f;
}
__device__ __forceinline__ f32x16 zero16() {
    f32x16 z;
#pragma unroll
    for (int i = 0; i < 16; i++) z[i] = 0.f;
    return z;
}
// pack two f32 -> one u32 of 2 bf16 (truncating): low half = a, high = b
__device__ __forceinline__ unsigned int pkbf(float a, float b) {
    return __builtin_amdgcn_perm(__builtin_bit_cast(unsigned int, b),
                                 __builtin_bit_cast(unsigned int, a), 0x07060302u);
}
// key permutation within a 16-block matching the 32x32 C/D row map
// (involution: swaps 4..7 <-> 8..11)
__device__ __forceinline__ int perm16(int p) {
    return (p & 3) + 8 * ((p >> 2) & 1) + 4 * (p >> 3);
}

// ---------------------------------------------------------------------------
// prep: fp32->bf16 converts for x, w_qkv, w_proj + mask -> bf16 0/1 vector
// stored PERM16-PERMUTED within each 16-key block (for flash's lacc B-frag).
// ---------------------------------------------------------------------------
__global__ __launch_bounds__(256) void prep(const float* __restrict__ x,
                                            const float* __restrict__ wqkv,
                                            const float* __restrict__ wproj,
                                            const int* __restrict__ m,
                                            unsigned short* __restrict__ xb,
                                            unsigned short* __restrict__ wqkvb,
                                            unsigned short* __restrict__ wprojb,
                                            unsigned short* __restrict__ mb) {
    int blk = blockIdx.x, tid = threadIdx.x;
    if (blk < 8192) {
        const float* src; unsigned short* dst; int i;
        if (blk < 4096)      { src = x;     dst = xb;     i = blk * 256 + tid; }
        else if (blk < 7168) { src = wqkv;  dst = wqkvb;  i = (blk - 4096) * 256 + tid; }
        else                 { src = wproj; dst = wprojb; i = (blk - 7168) * 256 + tid; }
        f32x4 v = ((const f32x4*)src)[i];
        u16x4 o;
        o[0] = f2bf(v[0]); o[1] = f2bf(v[1]); o[2] = f2bf(v[2]); o[3] = f2bf(v[3]);
        ((u16x4*)dst)[i] = o;
    } else {
        int i = (blk - 8192) * 256 + tid;
        int src = (i & ~15) | perm16(i & 15);          // N=2048 % 16 == 0: stays in batch
        mb[i] = (m[src] == 0) ? (unsigned short)0 : (unsigned short)0x3F80;  // bf16 1.0
    }
}

// ---------------------------------------------------------------------------
// bf16 GEMM, C[M,N] = A[M,K] * B[N,K]^T, bf16 out.  128x128 tile, BK=64.
// 1D grid, XCD-chunked swizzle (requires nwg % 8 == 0, else identity).
// ---------------------------------------------------------------------------
__global__ __launch_bounds__(256) void gemm_bt(const unsigned short* __restrict__ A,
                                               const unsigned short* __restrict__ B,
                                               unsigned short* __restrict__ C,
                                               int M, int N, int K) {
    __shared__ unsigned short Al[128][64];
    __shared__ unsigned short Bl[128][64];
    const int tid  = threadIdx.x;
    const int lane = tid & 63;
    const int qd   = lane >> 4;     // quad 0..3
    const int cc   = lane & 15;
    const int wave = tid >> 6;
    const int wr   = wave >> 1, wc = wave & 1;
    // XCD swizzle: chunk the grid so consecutive M-panels share an XCD L2
    const int nbx  = N >> 7;                     // N-tiles
    const int nwg  = gridDim.x;
    int d = blockIdx.x;
    int s = (nwg % 8 == 0) ? (d % 8) * (nwg / 8) + d / 8 : d;
    const int m0   = (s / nbx) * 128, n0 = (s % nbx) * 128;
    unsigned short* Alf = &Al[0][0];
    unsigned short* Blf = &Bl[0][0];

    f32x4 acc[4][4];
#pragma unroll
    for (int i = 0; i < 4; i++)
#pragma unroll
        for (int j = 0; j < 4; j++) acc[i][j] = (f32x4){0.f, 0.f, 0.f, 0.f};

    for (int k0 = 0; k0 < K; k0 += 64) {
#pragma unroll
        for (int t = 0; t < 4; t++) {
            int idx = t * 256 + tid;                 // 0..1023
            int row = idx >> 3, sg = (idx & 7) ^ (row & 7);
            GLD_TO_LDS(A + (size_t)(m0 + row) * K + k0 + sg * 8, Alf + idx * 8);
            GLD_TO_LDS(B + (size_t)(n0 + row) * K + k0 + sg * 8, Blf + idx * 8);
        }
        __syncthreads();
#pragma unroll
        for (int ks = 0; ks < 64; ks += 32) {
            const int s4 = ks >> 3;                  // 0 or 4
            s16x8 af[4], bf[4];
#pragma unroll
            for (int i = 0; i < 4; i++) {
                int r = wr * 64 + i * 16 + cc;
                af[i] = *(const s16x8*)&Al[r][((s4 + qd) ^ (r & 7)) * 8];
            }
#pragma unroll
            for (int j = 0; j < 4; j++) {
                int r = wc * 64 + j * 16 + cc;
                bf[j] = *(const s16x8*)&Bl[r][((s4 + qd) ^ (r & 7)) * 8];
            }
#pragma unroll
            for (int i = 0; i < 4; i++)
#pragma unroll
                for (int j = 0; j < 4; j++)
                    acc[i][j] = MFMA_BF16(af[i], bf[j], acc[i][j]);
        }
        __syncthreads();
    }
    // epilogue: C/D layout col=lane&15, row=quad*4+reg
#pragma unroll
    for (int i = 0; i < 4; i++)
#pragma unroll
        for (int j = 0; j < 4; j++)
#pragma unroll
            for (int r = 0; r < 4; r++) {
                int row = m0 + wr * 64 + i * 16 + qd * 4 + r;
                int col = n0 + wc * 64 + j * 16 + cc;
                C[(size_t)row * N + col] = f2bf(acc[i][j][r]);
            }
}

// ---------------------------------------------------------------------------
// RoPE + scatter: qkv[4096,3072] bf16 -> Q[B,H,N,D] (scaled by SCL), K (RoPE'd),
// V transposed -> Vt[B,H,D,N] with masked-key rows zeroed AND the key axis
// perm16-permuted within each 16-key block (flash PV B-frag order).
// ---------------------------------------------------------------------------
__global__ __launch_bounds__(256) void rope_scatter(const unsigned short* __restrict__ qkv,
                                                    const int* __restrict__ msk,
                                                    unsigned short* __restrict__ Q,
                                                    unsigned short* __restrict__ Kg,
                                                    unsigned short* __restrict__ Vt) {
    const int N = 2048, H = 16, D = 64, C3 = 3072;
    const float SCL = 0.18033688f;              // 0.125 * log2(e), folded into Q
    __shared__ unsigned short vl[64][65];       // +1 pad for transpose reads
    const int nt = blockIdx.x, h = blockIdx.y, b = blockIdx.z;
    const int n0 = nt * 64;
    const int tid = threadIdx.x;
    const size_t bh = (size_t)b * H + h;
#pragma unroll
    for (int it = 0; it < 2; it++) {
        int idx = tid + it * 256;           // 0..511
        int row = idx >> 3, seg = idx & 7;
        int d0 = seg * 8;
        int n = n0 + row;
        size_t rb = ((size_t)b * N + n) * C3;
        int keep = msk[(size_t)b * N + n];
        u16x8 qv = *(const u16x8*)&qkv[rb + h * 64 + d0];
        u16x8 qp = *(const u16x8*)&qkv[rb + h * 64 + (d0 ^ 32)];
        u16x8 kv = *(const u16x8*)&qkv[rb + 1024 + h * 64 + d0];
        u16x8 kp = *(const u16x8*)&qkv[rb + 1024 + h * 64 + (d0 ^ 32)];
        u16x8 vv = *(const u16x8*)&qkv[rb + 2048 + h * 64 + d0];
        u16x8 qo, ko;
        float sgn = (d0 < 32) ? -1.0f : 1.0f;   // rotate_half sign
#pragma unroll
        for (int j = 0; j < 8; j++) {
            int jj = (d0 & 31) + j;                              // freq index
            float th = (float)n * exp2f(-0.34375f * (float)jj);  // 2048^(-jj/32)
            float cth = cosf(th), sth = sinf(th);
            qo[j] = f2bf((bf2f(qv[j]) * cth + sgn * bf2f(qp[j]) * sth) * SCL);
            ko[j] = f2bf(bf2f(kv[j]) * cth + sgn * bf2f(kp[j]) * sth);
            vl[row][d0 + j] = keep ? vv[j] : (unsigned short)0;
        }
        *(u16x8*)&Q[(bh * N + n) * D + d0]  = qo;
        *(u16x8*)&Kg[(bh * N + n) * D + d0] = ko;
    }
    __syncthreads();
    // transposed V write: Vt[b,h,d, n-permuted]: Vt[.., 16t+p] = V[16t+perm16(p)]
#pragma unroll
    for (int it = 0; it < 2; it++) {
        int idx = tid + it * 256;
        int drow = idx >> 3, nseg = idx & 7;
        u16x8 ov;
#pragma unroll
        for (int j = 0; j < 8; j++) {
            int cpos = nseg * 8 + j;
            int srcl = (cpos & ~15) | perm16(cpos & 15);
            ov[j] = vl[srcl][drow];
        }
        *(u16x8*)&Vt[(bh * D + drow) * N + n0 + nseg * 8] = ov;
    }
}

// ---------------------------------------------------------------------------
// Flash attention R12: 32x32x16 MFMA, 4 waves x 32 q-rows, in-register P.
// S^T = mfma32(K, Q): lane holds P[q=lane&31][key=kg*32+(r&3)+8(r>>2)+4*hi].
// PV A-frag = DIRECT pack of p[0..7] / p[8..15]; V and mask are perm16-
// pre-permuted so B element (hi,j) carries the same key.  No P LDS, no
// cross-lane ops.  l = P @ mask via mfma32.  Double-buffered K/V staging.
// 1D grid (512 = 8 x 64), XCD-chunked swizzle: each XCD serves 4 (b,h) pairs
// x 16 q-tiles -> K/V working set 2 MB fits the 4 MB per-XCD L2.
// ---------------------------------------------------------------------------
__global__ __launch_bounds__(256, 2) void flash_attn(const unsigned short* __restrict__ Q,
                                                     const unsigned short* __restrict__ Kg,
                                                     const unsigned short* __restrict__ Vt,
                                                     const unsigned short* __restrict__ mb,
                                                     unsigned short* __restrict__ Og) {
    const int N = 2048, H = 16, D = 64;
    __shared__ unsigned short Kl0[64][64], Kl1[64][64];   // [key][d] swizzled
    __shared__ unsigned short Vl0[64][64], Vl1[64][64];   // [d][key-perm] swizzled
    const int tid  = threadIdx.x;
    const int lane = tid & 63;
    const int wave = tid >> 6;                 // 0..3
    const int c    = lane & 31;                // q (and K-row / V-row) index
    const int hi   = lane >> 5;                // 0/1: k-half of fragments
    // XCD swizzle: 512 blocks = 8 XCDs x 64; chunk so each XCD gets 4 (b,h)
    int dd = blockIdx.x;
    int sw = (dd & 7) * 64 + (dd >> 3);
    const int qt = sw & 15, h = (sw >> 4) & 15, b = sw >> 8;
    const int q0 = qt * 128;
    const size_t bh = (size_t)b * H + h;

    // Q B-frags: B[n=q=lane&31][k=d=kd*16+hi*8+j]  (Q already scaled by SCL)
    s16x8 qf[4];
    {
        const unsigned short* Qb = Q + (bh * N + q0 + wave * 32 + c) * D;
#pragma unroll
        for (int kd = 0; kd < 4; kd++) qf[kd] = *(const s16x8*)(Qb + kd * 16 + hi * 8);
    }

    f32x16 o[2], lacc;
    o[0] = zero16(); o[1] = zero16(); lacc = zero16();

    const unsigned short* Kbase = Kg + bh * N * D;
    const unsigned short* Vbase = Vt + bh * D * N;
    const unsigned short* mbase = mb + (size_t)b * N;   // perm16'd bf16 0/1 mask
    const int row_s = tid >> 3, sg_s = (tid & 7) ^ ((tid >> 3) & 7);
    const int row_s2 = (tid + 256) >> 3, sg_s2 = (tid & 7) ^ (((tid + 256) >> 3) & 7);

    auto issue = [&](int k0, unsigned short* Kb, unsigned short* Vb) {
        GLD_TO_LDS(Kbase + (size_t)(k0 + row_s) * D + sg_s * 8,   Kb + tid * 8);
        GLD_TO_LDS(Vbase + (size_t)row_s * N + k0 + sg_s * 8,     Vb + tid * 8);
        GLD_TO_LDS(Kbase + (size_t)(k0 + row_s2) * D + sg_s2 * 8, Kb + (tid + 256) * 8);
        GLD_TO_LDS(Vbase + (size_t)row_s2 * N + k0 + sg_s2 * 8,   Vb + (tid + 256) * 8);
    };

    auto compute = [&](int k0, const unsigned short (*Kb)[64], const unsigned short (*Vb)[64]) {
        // ---- QK^T: S^T[kg] = K[kg] x Q over D=64 (4 k-slices) ------------
        f32x16 sst[2];
        __builtin_amdgcn_s_setprio(1);
#pragma unroll
        for (int kg = 0; kg < 2; kg++) {
            int kr = kg * 32 + c;
            f32x16 s = zero16();
#pragma unroll
            for (int kd = 0; kd < 4; kd++) {
                s16x8 kf = *(const s16x8*)&Kb[kr][((kd * 2 + hi) ^ (kr & 7)) * 8];
                s = MFMA32_BF16(kf, qf[kd], s);
            }
            sst[kg] = s;
        }
        __builtin_amdgcn_s_setprio(0);

        // ---- exp2 + DIRECT in-register pack -> two PV A-frags per kg -----
        // p[r] holds key kg*32+(r&3)+8(r>>2)+4hi; A element j of pa[half]
        // carries key kg*32+half*16+perm16(hi*8+j) — matching pre-permuted V.
        auto packkg = [&](int kg, s16x8* pa) {
            float p[16];
#pragma unroll
            for (int r = 0; r < 16; r++) p[r] = __builtin_amdgcn_exp2f(sst[kg][r]);
#pragma unroll
            for (int half = 0; half < 2; half++) {
                int bs = half * 8;
                u32x4 w = { pkbf(p[bs + 0], p[bs + 1]), pkbf(p[bs + 2], p[bs + 3]),
                            pkbf(p[bs + 4], p[bs + 5]), pkbf(p[bs + 6], p[bs + 7]) };
                pa[half] = __builtin_bit_cast(s16x8, w);
            }
        };

        // ---- O += P V ; l += P @ mask for one 16-key slice ---------------
        auto pvks = [&](int ks, s16x8 pf) {
            s16x8 mfr = *(const s16x8*)&mbase[k0 + ks * 16 + hi * 8];
            __builtin_amdgcn_s_setprio(1);
            lacc = MFMA32_BF16(pf, mfr, lacc);
#pragma unroll
            for (int db = 0; db < 2; db++) {
                int vr = db * 32 + c;
                s16x8 vf = *(const s16x8*)&Vb[vr][((ks * 2 + hi) ^ (vr & 7)) * 8];
                o[db] = MFMA32_BF16(pf, vf, o[db]);
            }
            __builtin_amdgcn_s_setprio(0);
        };

        s16x8 pa[2];
        packkg(0, pa);            // keys 0..31 (overlaps kg=1 S-MFMA latency)
        pvks(0, pa[0]);
        pvks(1, pa[1]);
        packkg(1, pa);            // keys 32..63 overlap PV MFMA latency
        pvks(2, pa[0]);
        pvks(3, pa[1]);
    };

    issue(0, &Kl0[0][0], &Vl0[0][0]);
    __syncthreads();
    for (int it = 0; it < 32; it += 2) {
        int k0 = it * 64;
        if (it + 1 < 32) issue(k0 + 64, &Kl1[0][0], &Vl1[0][0]);
        compute(k0, Kl0, Vl0);
        __syncthreads();
        if (it + 2 < 32) issue(k0 + 128, &Kl0[0][0], &Vl0[0][0]);
        compute(k0 + 64, Kl1, Vl1);
        __syncthreads();
    }

    // epilogue: row q = q0 + wave*32 + (r&3)+8*(r>>2)+4*hi; col d = db*32 + c
    float linv[16];
#pragma unroll
    for (int r = 0; r < 16; r++) linv[r] = 1.0f / lacc[r];
#pragma unroll
    for (int db = 0; db < 2; db++)
#pragma unroll
        for (int r = 0; r < 16; r++) {
            int n = q0 + wave * 32 + (r & 3) + 8 * (r >> 2) + 4 * hi;
            Og[((size_t)b * N + n) * 1024 + h * 64 + db * 32 + c] =
                f2bf(o[db][r] * linv[r]);
        }
}

// ---------------------------------------------------------------------------
// Projection GEMM: out[4096,1024] = attno[4096,1024] @ w_proj^T + bias, fp32.
// 1D grid (512 = 8 x 64), XCD-chunked swizzle.
// ---------------------------------------------------------------------------
__global__ __launch_bounds__(256) void gemm_proj(const unsigned short* __restrict__ A,
                                                 const unsigned short* __restrict__ B,
                                                 float* __restrict__ C,
                                                 const float* __restrict__ bias) {
    const int NN = 1024, K = 1024;
    __shared__ unsigned short Al[128][64];
    __shared__ unsigned short Bl[64][64];
    const int tid  = threadIdx.x;
    const int lane = tid & 63;
    const int qd   = lane >> 4;
    const int cc   = lane & 15;
    const int wave = tid >> 6;
    const int wr   = wave >> 1, wc = wave & 1;
    int dd = blockIdx.x;                        // 512 = 8 x 64
    int sw = (dd & 7) * 64 + (dd >> 3);
    const int m0   = (sw >> 4) * 128, n0 = (sw & 15) * 64;
    unsigned short* Alf = &Al[0][0];
    unsigned short* Blf = &Bl[0][0];

    f32x4 acc[4][2];
#pragma unroll
    for (int i = 0; i < 4; i++)
#pragma unroll
        for (int j = 0; j < 2; j++) acc[i][j] = (f32x4){0.f, 0.f, 0.f, 0.f};

    for (int k0 = 0; k0 < K; k0 += 64) {
#pragma unroll
        for (int t = 0; t < 4; t++) {
            int idx = t * 256 + tid;
            int row = idx >> 3, sg = (idx & 7) ^ (row & 7);
            GLD_TO_LDS(A + (size_t)(m0 + row) * K + k0 + sg * 8, Alf + idx * 8);
        }
#pragma unroll
        for (int t = 0; t < 2; t++) {
            int idx = t * 256 + tid;
            int row = idx >> 3, sg = (idx & 7) ^ (row & 7);
            GLD_TO_LDS(B + (size_t)(n0 + row) * K + k0 + sg * 8, Blf + idx * 8);
        }
        __syncthreads();
#pragma unroll
        for (int ks = 0; ks < 64; ks += 32) {
            const int s4 = ks >> 3;
            s16x8 af[4], bf[2];
#pragma unroll
            for (int i = 0; i < 4; i++) {
                int r = wr * 64 + i * 16 + cc;
                af[i] = *(const s16x8*)&Al[r][((s4 + qd) ^ (r & 7)) * 8];
            }
#pragma unroll
            for (int j = 0; j < 2; j++) {
                int r = wc * 32 + j * 16 + cc;
                bf[j] = *(const s16x8*)&Bl[r][((s4 + qd) ^ (r & 7)) * 8];
            }
#pragma unroll
            for (int i = 0; i < 4; i++)
#pragma unroll
                for (int j = 0; j < 2; j++)
                    acc[i][j] = MFMA_BF16(af[i], bf[j], acc[i][j]);
        }
        __syncthreads();
    }
#pragma unroll
    for (int i = 0; i < 4; i++)
#pragma unroll
        for (int j = 0; j < 2; j++)
#pragma unroll
            for (int r = 0; r < 4; r++) {
                int row = m0 + wr * 64 + i * 16 + qd * 4 + r;
                int col = n0 + wc * 32 + j * 16 + cc;
                C[(size_t)row * NN + col] = acc[i][j][r] + bias[col];
            }
}

// ---------------------------------------------------------------------------
extern "C" void kernel_launch(void* const* d_in, const int* in_sizes, int n_in,
                              void* d_out, int out_size, void* d_ws, size_t ws_size,
                              hipStream_t stream) {
    const float* x      = (const float*)d_in[0];
    const float* w_qkv  = (const float*)d_in[1];
    const float* w_proj = (const float*)d_in[2];
    const float* b_proj = (const float*)d_in[3];
    const int*   mask   = (const int*)d_in[4];
    float* out = (float*)d_out;

    // workspace layout (bf16 elements), ~72 MB
    unsigned short* ws     = (unsigned short*)d_ws;
    unsigned short* xb     = ws;                                  // 4096*1024
    unsigned short* wqkvb  = xb     + (size_t)4096 * 1024;        // 3072*1024
    unsigned short* wprojb = wqkvb  + (size_t)3072 * 1024;        // 1024*1024
    unsigned short* qkv    = wprojb + (size_t)1024 * 1024;        // 4096*3072
    unsigned short* Qm     = qkv    + (size_t)4096 * 3072;        // 32*2048*64
    unsigned short* Km     = Qm     + (size_t)32 * 2048 * 64;
    unsigned short* Vtm    = Km     + (size_t)32 * 2048 * 64;
    unsigned short* attno  = Vtm    + (size_t)32 * 2048 * 64;     // 4096*1024
    unsigned short* maskbf = attno  + (size_t)4096 * 1024;        // 2*2048 bf16

    // converts + perm16'd bf16 mask vector, one launch
    prep<<<8208, 256, 0, stream>>>(x, w_qkv, w_proj, mask, xb, wqkvb, wprojb, maskbf);
    // qkv = x @ w_qkv^T   [4096, 3072]   (768 blocks = 8 x 96, XCD-swizzled)
    gemm_bt<<<768, 256, 0, stream>>>(xb, wqkvb, qkv, 4096, 3072, 1024);
    // RoPE + scatter to Q (SCL-scaled) / K [B,H,N,D]; Vt [B,H,D,N] perm16'd + masked rows zeroed
    rope_scatter<<<dim3(32, 16, 2), 256, 0, stream>>>(qkv, mask, Qm, Km, Vtm);
    // attention: 128-row Q tiles, 4 waves x 32 q-rows, 32x32 MFMA, in-reg P
    // (512 blocks = 8 x 64, XCD-swizzled)
    flash_attn<<<512, 256, 0, stream>>>(Qm, Km, Vtm, maskbf, attno);
    // out = attn_out @ w_proj^T + b_proj   (512 blocks = 8 x 64, XCD-swizzled)
    gemm_proj<<<512, 256, 0, stream>>>(attno, wprojb, out, b_proj);
}